// Round 1
// baseline (28.581 us; speedup 1.0000x reference)
//
#include <hip/hip_runtime.h>

#define T_LEN   2097152
#define CHUNK   8
#define BLOCK   256
#define NBLK    (T_LEN / (CHUNK * BLOCK))   // 1024
#define NWAVE   (BLOCK / 64)                // 4
#define FINAL_PER (NBLK / 256)              // 4

// 2x2 matrix in log-space, row-major: [ [a,b], [c,d] ]  (a=[0][0], b=[0][1], c=[1][0], d=[1][1])
struct M2 { float a, b, c, d; };

__device__ __forceinline__ float lse2(float x, float y) {
    float m = fmaxf(x, y);
    float d = fminf(x, y) - m;          // <= 0, exp never overflows
    return m + __logf(1.0f + __expf(d));
}

// log-semiring matmul: C[i][j] = lse_k(A[i][k] + B[k][j]).  Associative, NOT commutative.
__device__ __forceinline__ M2 mm(const M2 A, const M2 B) {
    M2 C;
    C.a = lse2(A.a + B.a, A.b + B.c);
    C.b = lse2(A.a + B.b, A.b + B.d);
    C.c = lse2(A.c + B.a, A.d + B.c);
    C.d = lse2(A.c + B.b, A.d + B.d);
    return C;
}

// Order-preserving 64-lane butterfly: after mask m, each lane holds the in-lane-order
// product of its 2m-aligned group. gold partial g is a plain sum (commutative).
__device__ __forceinline__ void wave_reduce(M2& P, float& g, int lane) {
    #pragma unroll
    for (int m = 1; m < 64; m <<= 1) {
        M2 O;
        O.a = __shfl_xor(P.a, m);
        O.b = __shfl_xor(P.b, m);
        O.c = __shfl_xor(P.c, m);
        O.d = __shfl_xor(P.d, m);
        g  += __shfl_xor(g, m);
        bool hi = (lane & m) != 0;      // my group comes AFTER partner's group
        M2 X, Y;
        X.a = hi ? O.a : P.a;  X.b = hi ? O.b : P.b;
        X.c = hi ? O.c : P.c;  X.d = hi ? O.d : P.d;
        Y.a = hi ? P.a : O.a;  Y.b = hi ? P.b : O.b;
        Y.c = hi ? P.c : O.c;  Y.d = hi ? P.d : O.d;
        P = mm(X, Y);
    }
}

__global__ __launch_bounds__(BLOCK) void crf_partial(
    const float* __restrict__ em,      // [T,2]
    const int*   __restrict__ label,   // [T]
    const int*   __restrict__ wst,     // [T] in 0..2
    const int*   __restrict__ pst,     // [T] in 0..19
    const float* __restrict__ w2w,     // [2,2,2]
    const float* __restrict__ pos,     // [19,2,2]
    float* __restrict__ outP,          // [NBLK,4]
    float* __restrict__ outG)          // [NBLK]
{
    __shared__ float4 comb[60];        // comb[w*20+p] = w2w_sub[w] + pos_sub[p], row-major 2x2
    __shared__ float4 wP[NWAVE];
    __shared__ float  wG[NWAVE];

    const int tid = threadIdx.x;
    if (tid < 60) {
        const int w = tid / 20, p = tid % 20;
        float v0 = 0.f, v1 = 0.f, v2 = 0.f, v3 = 0.f;
        if (w < 2)  { v0 += w2w[w*4+0]; v1 += w2w[w*4+1]; v2 += w2w[w*4+2]; v3 += w2w[w*4+3]; }
        if (p < 19) { v0 += pos[p*4+0]; v1 += pos[p*4+1]; v2 += pos[p*4+2]; v3 += pos[p*4+3]; }
        comb[tid] = make_float4(v0, v1, v2, v3);
    }
    __syncthreads();

    const int t0 = (blockIdx.x * BLOCK + tid) * CHUNK;

    // Coalesced vector loads of this thread's contiguous chunk.
    float4 evec[CHUNK/2];
    #pragma unroll
    for (int k = 0; k < CHUNK/2; ++k) evec[k] = ((const float4*)(em + 2*(long)t0))[k];
    const float* e = (const float*)evec;           // e[2*k + j]

    int4 lvec[CHUNK/4], wvec[CHUNK/4], pvec[CHUNK/4];
    #pragma unroll
    for (int k = 0; k < CHUNK/4; ++k) {
        lvec[k] = ((const int4*)(label + t0))[k];
        wvec[k] = ((const int4*)(wst   + t0))[k];
        pvec[k] = ((const int4*)(pst   + t0))[k];
    }
    const int* lb = (const int*)lvec;
    const int* wv = (const int*)wvec;
    const int* pv = (const int*)pvec;

    // ---- partition-function partial: fold CHUNK step matrices in order ----
    // step 0 initializes P = M[t0]:  M[i][j] = e[j] + c[i][j]
    float4 c0 = comb[wv[0]*20 + pv[0]];
    M2 P;
    P.a = e[0] + c0.x;  P.b = e[1] + c0.y;
    P.c = e[0] + c0.z;  P.d = e[1] + c0.w;

    #pragma unroll
    for (int k = 1; k < CHUNK; ++k) {
        float4 c = comb[wv[k]*20 + pv[k]];
        float e0 = e[2*k], e1 = e[2*k+1];
        M2 Q;   // Q[i][j] = e[j] + lse(P[i][0]+c[0][j], P[i][1]+c[1][j])
        Q.a = e0 + lse2(P.a + c.x, P.b + c.z);
        Q.b = e1 + lse2(P.a + c.y, P.b + c.w);
        Q.c = e0 + lse2(P.c + c.x, P.d + c.z);
        Q.d = e1 + lse2(P.c + c.y, P.d + c.w);
        P = Q;
    }

    // ---- gold-score partial ----
    // trans[0] is the zero matrix by construction (wst[0]==2, pst[0]==19), so the
    // t==0 "transition" add is exactly 0 — no special case beyond the label[-1] guard.
    float g = 0.f;
    int prev = (t0 == 0) ? 0 : label[t0 - 1];
    #pragma unroll
    for (int k = 0; k < CHUNK; ++k) {
        const int l = lb[k];
        g += e[2*k + l];
        float4 c = comb[wv[k]*20 + pv[k]];
        g += prev ? (l ? c.w : c.z) : (l ? c.y : c.x);
        prev = l;
    }

    // ---- reductions (fixed order -> deterministic) ----
    const int lane = tid & 63;
    wave_reduce(P, g, lane);

    const int wid = tid >> 6;
    if (lane == 0) { wP[wid] = make_float4(P.a, P.b, P.c, P.d); wG[wid] = g; }
    __syncthreads();
    if (tid == 0) {
        float4 q = wP[0];
        M2 R = { q.x, q.y, q.z, q.w };
        float gg = wG[0];
        #pragma unroll
        for (int w = 1; w < NWAVE; ++w) {
            float4 t = wP[w];
            M2 B = { t.x, t.y, t.z, t.w };
            R = mm(R, B);
            gg += wG[w];
        }
        ((float4*)outP)[blockIdx.x] = make_float4(R.a, R.b, R.c, R.d);
        outG[blockIdx.x] = gg;
    }
}

__global__ __launch_bounds__(256) void crf_final(
    const float* __restrict__ inP,     // [NBLK,4]
    const float* __restrict__ inG,     // [NBLK]
    float* __restrict__ out)           // [2] = {gold, total}
{
    __shared__ float4 wP[4];
    __shared__ float  wG[4];

    const int tid  = threadIdx.x;
    const int base = tid * FINAL_PER;

    float4 q = ((const float4*)inP)[base];
    M2 P = { q.x, q.y, q.z, q.w };
    float g = inG[base];
    #pragma unroll
    for (int k = 1; k < FINAL_PER; ++k) {
        float4 r = ((const float4*)inP)[base + k];
        M2 B = { r.x, r.y, r.z, r.w };
        P = mm(P, B);
        g += inG[base + k];
    }

    const int lane = tid & 63;
    wave_reduce(P, g, lane);

    const int wid = tid >> 6;
    if (lane == 0) { wP[wid] = make_float4(P.a, P.b, P.c, P.d); wG[wid] = g; }
    __syncthreads();
    if (tid == 0) {
        float4 q0 = wP[0];
        M2 R = { q0.x, q0.y, q0.z, q0.w };
        float gg = wG[0];
        #pragma unroll
        for (int w = 1; w < 4; ++w) {
            float4 t = wP[w];
            M2 B = { t.x, t.y, t.z, t.w };
            R = mm(R, B);
            gg += wG[w];
        }
        // alpha0 == 0  =>  total = lse over all 4 entries of the full product.
        out[0] = gg;
        out[1] = lse2(lse2(R.a, R.b), lse2(R.c, R.d));
    }
}

extern "C" void kernel_launch(void* const* d_in, const int* in_sizes, int n_in,
                              void* d_out, int out_size, void* d_ws, size_t ws_size,
                              hipStream_t stream) {
    const float* em    = (const float*)d_in[0];
    const int*   label = (const int*)  d_in[1];
    const int*   wst   = (const int*)  d_in[2];
    const int*   pst   = (const int*)  d_in[3];
    const float* w2w   = (const float*)d_in[4];
    const float* pos   = (const float*)d_in[5];
    float* out = (float*)d_out;

    float* outP = (float*)d_ws;          // NBLK*4 floats (16 KB)
    float* outG = outP + NBLK * 4;       // NBLK floats  (4 KB)

    crf_partial<<<NBLK, BLOCK, 0, stream>>>(em, label, wst, pst, w2w, pos, outP, outG);
    crf_final<<<1, 256, 0, stream>>>(outP, outG, out);
}

// Round 2
// 18.589 us; speedup vs baseline: 1.5375x; 1.5375x over previous
//
#include <hip/hip_runtime.h>

#define T_LEN   2097152
#define CHUNK   8
#define BLOCK   256
#define NBLK    (T_LEN / (CHUNK * BLOCK))   // 1024
#define NWAVE   (BLOCK / 64)                // 4
#define FINAL_PER (NBLK / 256)              // 4

#define LOG2E 1.44269504088896340736f
#define LN2   0.69314718055994530942f

// Native base-2 transcendentals (v_exp_f32 / v_log_f32 ARE base-2 on gfx9xx).
__device__ __forceinline__ float fexp2(float x) {
#if __has_builtin(__builtin_amdgcn_exp2f)
    return __builtin_amdgcn_exp2f(x);
#else
    return __expf(x * LN2);
#endif
}
__device__ __forceinline__ float flog2(float x) {
#if __has_builtin(__builtin_amdgcn_logf)
    return __builtin_amdgcn_logf(x);
#else
    return __logf(x) * LOG2E;
#endif
}

// logsumexp in the log2-scaled domain: all scores are (natural-log score)*log2e.
// lse2b(x,y) = max + log2(1 + 2^(min-max)).  7 VALU ops, 2 transcendental.
__device__ __forceinline__ float lse2b(float x, float y) {
    float m = fmaxf(x, y);
    float d = fminf(x, y) - m;          // <= 0, exp2 never overflows
    return m + flog2(1.0f + fexp2(d));
}

// 2x2 matrix in log2-scaled space, row-major entries a=[0][0] b=[0][1] c=[1][0] d=[1][1]
struct M2 { float a, b, c, d; };

// log-semiring matmul (scaled domain). Associative, NOT commutative.
__device__ __forceinline__ M2 mm(const M2 A, const M2 B) {
    M2 C;
    C.a = lse2b(A.a + B.a, A.b + B.c);
    C.b = lse2b(A.a + B.b, A.b + B.d);
    C.c = lse2b(A.c + B.a, A.d + B.c);
    C.d = lse2b(A.c + B.b, A.d + B.d);
    return C;
}

// Order-preserving 64-lane butterfly; g is a plain (commutative) sum.
__device__ __forceinline__ void wave_reduce(M2& P, float& g, int lane) {
    #pragma unroll
    for (int m = 1; m < 64; m <<= 1) {
        M2 O;
        O.a = __shfl_xor(P.a, m);
        O.b = __shfl_xor(P.b, m);
        O.c = __shfl_xor(P.c, m);
        O.d = __shfl_xor(P.d, m);
        g  += __shfl_xor(g, m);
        bool hi = (lane & m) != 0;      // my group comes AFTER partner's group
        M2 X, Y;
        X.a = hi ? O.a : P.a;  X.b = hi ? O.b : P.b;
        X.c = hi ? O.c : P.c;  X.d = hi ? O.d : P.d;
        Y.a = hi ? P.a : O.a;  Y.b = hi ? P.b : O.b;
        Y.c = hi ? P.c : O.c;  Y.d = hi ? P.d : O.d;
        P = mm(X, Y);
    }
}

__global__ __launch_bounds__(BLOCK) void crf_partial(
    const float* __restrict__ em,      // [T,2]
    const int*   __restrict__ label,   // [T]
    const int*   __restrict__ wst,     // [T] in 0..2
    const int*   __restrict__ pst,     // [T] in 0..19
    const float* __restrict__ w2w,     // [2,2,2]
    const float* __restrict__ pos,     // [19,2,2]
    float* __restrict__ outP,          // [NBLK,4]  (scaled domain)
    float* __restrict__ outG)          // [NBLK]    (scaled domain)
{
    __shared__ float4 comb[60];        // comb[w*20+p] = (w2w_sub[w]+pos_sub[p]) * LOG2E
    __shared__ float4 wPs[NWAVE];
    __shared__ float  wGs[NWAVE];

    const int tid = threadIdx.x;
    if (tid < 60) {
        const int w = tid / 20, p = tid % 20;
        float v0 = 0.f, v1 = 0.f, v2 = 0.f, v3 = 0.f;
        if (w < 2)  { v0 += w2w[w*4+0]; v1 += w2w[w*4+1]; v2 += w2w[w*4+2]; v3 += w2w[w*4+3]; }
        if (p < 19) { v0 += pos[p*4+0]; v1 += pos[p*4+1]; v2 += pos[p*4+2]; v3 += pos[p*4+3]; }
        comb[tid] = make_float4(v0 * LOG2E, v1 * LOG2E, v2 * LOG2E, v3 * LOG2E);
    }
    __syncthreads();

    const int t0 = (blockIdx.x * BLOCK + tid) * CHUNK;

    // ---- loads: named registers only, no pointer-reinterpret of locals ----
    const float4* emv = (const float4*)(em + 2 * (size_t)t0);
    float4 E0 = emv[0], E1 = emv[1], E2 = emv[2], E3 = emv[3];
    const int4* lv = (const int4*)(label + t0);
    const int4* wv = (const int4*)(wst   + t0);
    const int4* pv = (const int4*)(pst   + t0);
    int4 L0 = lv[0], L1 = lv[1];
    int4 W0 = wv[0], W1 = wv[1];
    int4 Pq0 = pv[0], Pq1 = pv[1];
    int prev = (t0 == 0) ? 0 : label[t0 - 1];

    // scale emissions into log2 domain
    E0.x *= LOG2E; E0.y *= LOG2E; E0.z *= LOG2E; E0.w *= LOG2E;
    E1.x *= LOG2E; E1.y *= LOG2E; E1.z *= LOG2E; E1.w *= LOG2E;
    E2.x *= LOG2E; E2.y *= LOG2E; E2.z *= LOG2E; E2.w *= LOG2E;
    E3.x *= LOG2E; E3.y *= LOG2E; E3.z *= LOG2E; E3.w *= LOG2E;

    // ---- prefetch all 8 transition matrices (independent LDS reads, overlap latency)
    float4 c0 = comb[W0.x*20 + Pq0.x];
    float4 c1 = comb[W0.y*20 + Pq0.y];
    float4 c2 = comb[W0.z*20 + Pq0.z];
    float4 c3 = comb[W0.w*20 + Pq0.w];
    float4 c4 = comb[W1.x*20 + Pq1.x];
    float4 c5 = comb[W1.y*20 + Pq1.y];
    float4 c6 = comb[W1.z*20 + Pq1.z];
    float4 c7 = comb[W1.w*20 + Pq1.w];

    // ---- fused fold: partition partial (P) + gold partial (g), one pass ----
    float Pa, Pb, Pc, Pd, g;

    // step 0: P = M[t0],  M[i][j] = e[j] + c[i][j]
    Pa = E0.x + c0.x;  Pb = E0.y + c0.y;
    Pc = E0.x + c0.z;  Pd = E0.y + c0.w;
    {
        const int l = L0.x;
        g  = l ? E0.y : E0.x;
        g += prev ? (l ? c0.w : c0.z) : (l ? c0.y : c0.x);
        prev = l;
    }

#define STEP(e0v, e1v, cc, ll)                                             \
    {                                                                      \
        const float e0 = (e0v), e1 = (e1v);                                \
        const float4 c = (cc);                                             \
        const int l = (ll);                                                \
        g += l ? e1 : e0;                                                  \
        g += prev ? (l ? c.w : c.z) : (l ? c.y : c.x);                     \
        prev = l;                                                          \
        float na = e0 + lse2b(Pa + c.x, Pb + c.z);                         \
        float nb = e1 + lse2b(Pa + c.y, Pb + c.w);                         \
        float nc = e0 + lse2b(Pc + c.x, Pd + c.z);                         \
        float nd = e1 + lse2b(Pc + c.y, Pd + c.w);                         \
        Pa = na; Pb = nb; Pc = nc; Pd = nd;                                \
    }

    STEP(E0.z, E0.w, c1, L0.y)
    STEP(E1.x, E1.y, c2, L0.z)
    STEP(E1.z, E1.w, c3, L0.w)
    STEP(E2.x, E2.y, c4, L1.x)
    STEP(E2.z, E2.w, c5, L1.y)
    STEP(E3.x, E3.y, c6, L1.z)
    STEP(E3.z, E3.w, c7, L1.w)
#undef STEP

    // ---- reductions (fixed order -> deterministic) ----
    M2 P = { Pa, Pb, Pc, Pd };
    const int lane = tid & 63;
    wave_reduce(P, g, lane);

    const int wid = tid >> 6;
    if (lane == 0) { wPs[wid] = make_float4(P.a, P.b, P.c, P.d); wGs[wid] = g; }
    __syncthreads();
    if (tid == 0) {
        float4 q = wPs[0];
        M2 R = { q.x, q.y, q.z, q.w };
        float gg = wGs[0];
        #pragma unroll
        for (int w = 1; w < NWAVE; ++w) {
            float4 t = wPs[w];
            M2 B = { t.x, t.y, t.z, t.w };
            R = mm(R, B);
            gg += wGs[w];
        }
        ((float4*)outP)[blockIdx.x] = make_float4(R.a, R.b, R.c, R.d);
        outG[blockIdx.x] = gg;
    }
}

__global__ __launch_bounds__(256) void crf_final(
    const float* __restrict__ inP,     // [NBLK,4] (scaled)
    const float* __restrict__ inG,     // [NBLK]   (scaled)
    float* __restrict__ out)           // [2] = {gold, total} (natural log)
{
    __shared__ float4 wPs[4];
    __shared__ float  wGs[4];

    const int tid  = threadIdx.x;
    const int base = tid * FINAL_PER;

    float4 q = ((const float4*)inP)[base];
    M2 P = { q.x, q.y, q.z, q.w };
    float g = inG[base];
    #pragma unroll
    for (int k = 1; k < FINAL_PER; ++k) {
        float4 r = ((const float4*)inP)[base + k];
        M2 B = { r.x, r.y, r.z, r.w };
        P = mm(P, B);
        g += inG[base + k];
    }

    const int lane = tid & 63;
    wave_reduce(P, g, lane);

    const int wid = tid >> 6;
    if (lane == 0) { wPs[wid] = make_float4(P.a, P.b, P.c, P.d); wGs[wid] = g; }
    __syncthreads();
    if (tid == 0) {
        float4 q0 = wPs[0];
        M2 R = { q0.x, q0.y, q0.z, q0.w };
        float gg = wGs[0];
        #pragma unroll
        for (int w = 1; w < 4; ++w) {
            float4 t = wPs[w];
            M2 B = { t.x, t.y, t.z, t.w };
            R = mm(R, B);
            gg += wGs[w];
        }
        // back to natural log: multiply scaled scores by ln2 once.
        out[0] = gg * LN2;
        out[1] = lse2b(lse2b(R.a, R.b), lse2b(R.c, R.d)) * LN2;
    }
}

extern "C" void kernel_launch(void* const* d_in, const int* in_sizes, int n_in,
                              void* d_out, int out_size, void* d_ws, size_t ws_size,
                              hipStream_t stream) {
    const float* em    = (const float*)d_in[0];
    const int*   label = (const int*)  d_in[1];
    const int*   wst   = (const int*)  d_in[2];
    const int*   pst   = (const int*)  d_in[3];
    const float* w2w   = (const float*)d_in[4];
    const float* pos   = (const float*)d_in[5];
    float* out = (float*)d_out;

    float* outP = (float*)d_ws;          // NBLK*4 floats (16 KB)
    float* outG = outP + NBLK * 4;       // NBLK floats  (4 KB)

    crf_partial<<<NBLK, BLOCK, 0, stream>>>(em, label, wst, pst, w2w, pos, outP, outG);
    crf_final<<<1, 256, 0, stream>>>(outP, outG, out);
}